// Round 1
// baseline (475.014 us; speedup 1.0000x reference)
//
#include <hip/hip_runtime.h>

#define TT 1024
#define NIN 6
#define NN 64
#define PF 3  // prefetch depth; 1023 = 340*3 + 3 -> clean main/tail split

__device__ __forceinline__ float rdl(float v, int l) {
  return __int_as_float(__builtin_amdgcn_readlane(__float_as_int(v), l));
}

__global__ void __launch_bounds__(64) rnn_scan_kernel(
    const float* __restrict__ u, const float* __restrict__ noise,
    const float* __restrict__ Wrec, const float* __restrict__ Win,
    float* __restrict__ out) {
  const int b = blockIdx.x;
  const int n = threadIdx.x;  // lane 0..63, owns state component n

  // Per-lane weights: W_rec row n (64 f32), W_in row n (6 f32). Static
  // indices after unroll -> stays in VGPRs (no scratch).
  float w[NN];
#pragma unroll
  for (int k = 0; k < NN; k += 4) {
    const float4 v = *reinterpret_cast<const float4*>(Wrec + n * NN + k);
    w[k] = v.x; w[k + 1] = v.y; w[k + 2] = v.z; w[k + 3] = v.w;
  }
  float win[NIN];
#pragma unroll
  for (int j = 0; j < NIN; ++j) win[j] = Win[n * NIN + j];

  const float scale = 0.09486832980505137f;  // sqrt(2*alpha*sigma_rec^2)

  const float* nzp = noise + (size_t)b * TT * NN + n;
  const float* up  = u + (size_t)b * TT * NIN;
  float* op = out + (size_t)b * TT * NN + n;

  // states[:,0,:] = 0
  op[0] = 0.0f;
  float s = 0.0f;

  // Prefetch rings: noise (per-lane, coalesced) and u (lanes 0..5 load the
  // 6 inputs for this (b,t); broadcast later via readlane).
  float nz[PF];
  float uu[PF];
#pragma unroll
  for (int i = 0; i < PF; ++i) {
    nz[i] = nzp[i * NN];
    uu[i] = (n < NIN) ? up[i * NIN + n] : 0.0f;
  }
  nzp += PF * NN;
  up  += PF * NIN;
  op  += NN;  // -> t=1 slot

  const int S = TT - 1;     // 1023 steps
  const int MAIN = S - PF;  // 1020 = 340 * PF

  for (int tb = 0; tb < MAIN; tb += PF) {
#pragma unroll
    for (int i = 0; i < PF; ++i) {
      const float nzc = nz[i];
      const float uc  = uu[i];
      // issue prefetch for step t+PF (fully covered by ~3 iters of compute)
      nz[i] = nzp[i * NN];
      uu[i] = (n < NIN) ? up[i * NIN + n] : 0.0f;

      // pre[n] = scale*noise + sum_k W_rec[n][k]*s[k] + sum_j W_in[n][j]*u[j]
      float a0 = scale * nzc;
      float a1 = 0.f, a2 = 0.f, a3 = 0.f;
#pragma unroll
      for (int k = 0; k < NN; k += 4) {
        a0 = fmaf(rdl(s, k + 0), w[k + 0], a0);
        a1 = fmaf(rdl(s, k + 1), w[k + 1], a1);
        a2 = fmaf(rdl(s, k + 2), w[k + 2], a2);
        a3 = fmaf(rdl(s, k + 3), w[k + 3], a3);
      }
      float pre = (a0 + a1) + (a2 + a3);
#pragma unroll
      for (int j = 0; j < NIN; ++j) pre = fmaf(rdl(uc, j), win[j], pre);

      const float r = fmaxf(pre, 0.0f);
      s = 0.8f * s + 0.2f * r;
      op[(size_t)i * NN] = s;  // states[b][t+1][n], coalesced
    }
    nzp += PF * NN;
    up  += PF * NIN;
    op  += PF * NN;
  }

  // tail: last PF steps, no further prefetch
#pragma unroll
  for (int i = 0; i < PF; ++i) {
    const float nzc = nz[i];
    const float uc  = uu[i];
    float a0 = scale * nzc;
    float a1 = 0.f, a2 = 0.f, a3 = 0.f;
#pragma unroll
    for (int k = 0; k < NN; k += 4) {
      a0 = fmaf(rdl(s, k + 0), w[k + 0], a0);
      a1 = fmaf(rdl(s, k + 1), w[k + 1], a1);
      a2 = fmaf(rdl(s, k + 2), w[k + 2], a2);
      a3 = fmaf(rdl(s, k + 3), w[k + 3], a3);
    }
    float pre = (a0 + a1) + (a2 + a3);
#pragma unroll
    for (int j = 0; j < NIN; ++j) pre = fmaf(rdl(uc, j), win[j], pre);

    const float r = fmaxf(pre, 0.0f);
    s = 0.8f * s + 0.2f * r;
    op[(size_t)i * NN] = s;
  }
}

extern "C" void kernel_launch(void* const* d_in, const int* in_sizes, int n_in,
                              void* d_out, int out_size, void* d_ws, size_t ws_size,
                              hipStream_t stream) {
  const float* u     = (const float*)d_in[0];
  const float* noise = (const float*)d_in[1];
  const float* Wrec  = (const float*)d_in[2];
  const float* Win   = (const float*)d_in[3];
  float* out = (float*)d_out;

  const int B = in_sizes[0] / (TT * NIN);  // 512
  hipLaunchKernelGGL(rnn_scan_kernel, dim3(B), dim3(64), 0, stream,
                     u, noise, Wrec, Win, out);
}

// Round 2
// 343.077 us; speedup vs baseline: 1.3846x; 1.3846x over previous
//
#include <hip/hip_runtime.h>

typedef float v2f __attribute__((ext_vector_type(2)));
typedef float v4f __attribute__((ext_vector_type(4)));

#define TT 1024
#define NIN 6
#define NN 64
#define PF 4  // prefetch depth (even -> static LDS ping-pong parity under unroll)
#define SCALE 0.09486832980505137f  // sqrt(2*alpha*sigma_rec^2)

__device__ __forceinline__ v2f pk_fma(v2f a, v2f b, v2f c) {
  return __builtin_elementwise_fma(a, b, c);  // -> v_pk_fma_f32
}

__global__ void __launch_bounds__(64) rnn_scan_kernel(
    const float* __restrict__ u, const float* __restrict__ noise,
    const float* __restrict__ Wrec, const float* __restrict__ Win,
    float* __restrict__ out) {
  const int b = blockIdx.x;
  const int n = threadIdx.x;  // lane owns state component n

  // Single wave per block: per-wave LDS ops execute in order; no barriers
  // (a __syncthreads here would emit s_waitcnt vmcnt(0) and kill the
  // global-load prefetch pipeline every step).
  __shared__ __align__(16) float smS[NN];      // state broadcast buffer
  __shared__ __align__(16) float smU[2][8];    // u ping-pong (6 used, pad 8)

  // Per-lane weights: W_rec row n as 32 f32 pairs (for v_pk_fma_f32).
  v2f w2[NN / 2];
#pragma unroll
  for (int k = 0; k < NN; k += 4) {
    const float4 v = *reinterpret_cast<const float4*>(Wrec + n * NN + k);
    w2[k / 2 + 0] = v2f{v.x, v.y};
    w2[k / 2 + 1] = v2f{v.z, v.w};
  }
  v2f win2[3];
#pragma unroll
  for (int j = 0; j < 3; ++j)
    win2[j] = v2f{Win[n * NIN + 2 * j + 0], Win[n * NIN + 2 * j + 1]};

  const float* nzp = noise + (size_t)b * TT * NN + n;
  const float* up  = u + (size_t)b * TT * NIN;
  float* op = out + (size_t)b * TT * NN + n;

  float s = 0.0f;
  op[0] = 0.0f;      // states[:,0,:] = 0
  smS[n] = 0.0f;     // s_0 broadcast
  if (n < NIN) smU[0][n] = up[n];  // u_0 (vmcnt-waited before ds_write)

  // Prefetch rings: slot t%PF holds data for step t.
  float nz[PF], uu[PF];
#pragma unroll
  for (int i = 0; i < PF; ++i) nz[i] = nzp[i * NN];  // noise rows 0..3
  uu[0] = 0.0f;  // filled at t=0 with u_4
  uu[1] = (n < NIN) ? up[1 * NIN + n] : 0.0f;
  uu[2] = (n < NIN) ? up[2 * NIN + n] : 0.0f;
  uu[3] = (n < NIN) ? up[3 * NIN + n] : 0.0f;

  nzp += PF * NN;
  op  += NN;  // -> row 1

  // ---- main: steps t = 0..1019 (refills always in-bounds: t+PF <= 1023)
  for (int tb = 0; tb < 1020; tb += PF) {
#pragma unroll
    for (int i = 0; i < PF; ++i) {      // t = tb + i, parity p = t&1 = i&1
      const int p = i & 1;
      // stage u_{t+1} into the other LDS half (disjoint from smU[p] reads)
      if (n < NIN) smU[p ^ 1][n] = uu[(i + 1) & (PF - 1)];
      // consume + refill rings (for step t+PF)
      const float nzc = nz[i];
      nz[i] = nzp[i * NN];
      uu[i] = (n < NIN) ? up[(i + PF) * NIN + n] : 0.0f;

      // pre[n] = scale*noise + W_in[n,:]@u_t + W_rec[n,:]@s_t
      v2f a0 = v2f{SCALE * nzc, 0.0f};
      v2f a1 = v2f{0.0f, 0.0f}, a2 = v2f{0.0f, 0.0f}, a3 = v2f{0.0f, 0.0f};
      {
        const v4f u03 = *reinterpret_cast<const v4f*>(&smU[p][0]);
        const v2f u45 = *reinterpret_cast<const v2f*>(&smU[p][4]);
        a0 = pk_fma(v2f{u03.x, u03.y}, win2[0], a0);
        a1 = pk_fma(v2f{u03.z, u03.w}, win2[1], a1);
        a2 = pk_fma(u45, win2[2], a2);
      }
      const v4f* svp4 = reinterpret_cast<const v4f*>(smS);
#pragma unroll
      for (int q = 0; q < 16; q += 2) {  // 16 broadcast ds_read_b128
        const v4f qa = svp4[q + 0];
        a0 = pk_fma(v2f{qa.x, qa.y}, w2[2 * q + 0], a0);
        a1 = pk_fma(v2f{qa.z, qa.w}, w2[2 * q + 1], a1);
        const v4f qb = svp4[q + 1];
        a2 = pk_fma(v2f{qb.x, qb.y}, w2[2 * q + 2], a2);
        a3 = pk_fma(v2f{qb.z, qb.w}, w2[2 * q + 3], a3);
      }
      const v2f at = (a0 + a1) + (a2 + a3);
      const float pre = at.x + at.y;
      const float r = fmaxf(pre, 0.0f);
      s = fmaf(0.2f, r, 0.8f * s);
      smS[n] = s;        // broadcast s_{t+1} (in-order DS: after this step's reads)
      op[i * NN] = s;    // states[b][t+1][n], coalesced
    }
    nzp += PF * NN;
    up  += PF * NIN;
    op  += PF * NN;
  }

  // ---- tail: t = 1020..1022, no refills
#pragma unroll
  for (int i = 0; i < 3; ++i) {
    const int p = i & 1;
    if (n < NIN) smU[p ^ 1][n] = uu[(i + 1) & (PF - 1)];
    const float nzc = nz[i];

    v2f a0 = v2f{SCALE * nzc, 0.0f};
    v2f a1 = v2f{0.0f, 0.0f}, a2 = v2f{0.0f, 0.0f}, a3 = v2f{0.0f, 0.0f};
    {
      const v4f u03 = *reinterpret_cast<const v4f*>(&smU[p][0]);
      const v2f u45 = *reinterpret_cast<const v2f*>(&smU[p][4]);
      a0 = pk_fma(v2f{u03.x, u03.y}, win2[0], a0);
      a1 = pk_fma(v2f{u03.z, u03.w}, win2[1], a1);
      a2 = pk_fma(u45, win2[2], a2);
    }
    const v4f* svp4 = reinterpret_cast<const v4f*>(smS);
#pragma unroll
    for (int q = 0; q < 16; q += 2) {
      const v4f qa = svp4[q + 0];
      a0 = pk_fma(v2f{qa.x, qa.y}, w2[2 * q + 0], a0);
      a1 = pk_fma(v2f{qa.z, qa.w}, w2[2 * q + 1], a1);
      const v4f qb = svp4[q + 1];
      a2 = pk_fma(v2f{qb.x, qb.y}, w2[2 * q + 2], a2);
      a3 = pk_fma(v2f{qb.z, qb.w}, w2[2 * q + 3], a3);
    }
    const v2f at = (a0 + a1) + (a2 + a3);
    const float pre = at.x + at.y;
    const float r = fmaxf(pre, 0.0f);
    s = fmaf(0.2f, r, 0.8f * s);
    smS[n] = s;
    op[i * NN] = s;
  }
}

extern "C" void kernel_launch(void* const* d_in, const int* in_sizes, int n_in,
                              void* d_out, int out_size, void* d_ws, size_t ws_size,
                              hipStream_t stream) {
  const float* u     = (const float*)d_in[0];
  const float* noise = (const float*)d_in[1];
  const float* Wrec  = (const float*)d_in[2];
  const float* Win   = (const float*)d_in[3];
  float* out = (float*)d_out;

  const int B = in_sizes[0] / (TT * NIN);  // 512
  hipLaunchKernelGGL(rnn_scan_kernel, dim3(B), dim3(64), 0, stream,
                     u, noise, Wrec, Win, out);
}

// Round 3
// 295.307 us; speedup vs baseline: 1.6085x; 1.1618x over previous
//
#include <hip/hip_runtime.h>

typedef float v2f __attribute__((ext_vector_type(2)));
typedef float v4f __attribute__((ext_vector_type(4)));

#define TT 1024
#define NIN 6
#define NN 64
#define CHUNK 32
#define NCHUNK 32
#define SCALE 0.09486832980505137f  // sqrt(2*alpha*sigma_rec^2)

__device__ __forceinline__ v2f pk_fma(v2f a, v2f b, v2f c) {
  return __builtin_elementwise_fma(a, b, c);  // -> v_pk_fma_f32
}

typedef const __attribute__((address_space(1))) unsigned int gu32;
typedef __attribute__((address_space(3))) unsigned int lu32;

__global__ void __launch_bounds__(64) rnn_scan_kernel(
    const float* __restrict__ u, const float* __restrict__ noise,
    const float* __restrict__ Wrec, const float* __restrict__ Win,
    float* __restrict__ out) {
  const int b = blockIdx.x;
  const int n = threadIdx.x;  // lane owns state component n

  // Single wave per block: same-wave DS ops execute in order -> no barriers.
  __shared__ __align__(16) float smS[NN];                // state broadcast
  __shared__ __align__(16) float smNz[2][CHUNK * NN];    // noise chunks (2 x 8KB)
  __shared__ __align__(16) float smU[2][CHUNK * NIN];    // u chunks (2 x 768B)

  const float* nzg = noise + (size_t)b * TT * NN;
  const float* ug  = u + (size_t)b * TT * NIN;
  float* op = out + (size_t)b * TT * NN + n;

  // ---- stage chunk 0 (latency hidden behind the weight loads below)
#pragma unroll
  for (int i = 0; i < 8; ++i)
    __builtin_amdgcn_global_load_lds((gu32*)(nzg + i * 256 + n * 4),
                                     (lu32*)(&smNz[0][i * 256]), 16, 0, 0);
#pragma unroll
  for (int j = 0; j < 3; ++j)
    __builtin_amdgcn_global_load_lds((gu32*)(ug + j * 64 + n),
                                     (lu32*)(&smU[0][j * 64]), 4, 0, 0);

  // ---- per-lane weights: W_rec row n as 32 f32 pairs, W_in row n as 3 pairs
  v2f w2[NN / 2];
#pragma unroll
  for (int k = 0; k < NN; k += 4) {
    const float4 v = *reinterpret_cast<const float4*>(Wrec + n * NN + k);
    w2[k / 2 + 0] = v2f{v.x, v.y};
    w2[k / 2 + 1] = v2f{v.z, v.w};
  }
  v2f win2[3];
#pragma unroll
  for (int j = 0; j < 3; ++j)
    win2[j] = v2f{Win[n * NIN + 2 * j + 0], Win[n * NIN + 2 * j + 1]};

  float s = 0.0f;
  smS[n] = 0.0f;   // s_0 broadcast (same-wave in-order DS)
  op[0] = 0.0f;    // states[:,0,:] = 0

  // Drain everything once (weights + chunk0 + zero-store) -> clean vmcnt
  // accounting for the hand-counted waits in the loop.
  asm volatile("s_waitcnt vmcnt(0)" ::: "memory");
  __builtin_amdgcn_sched_barrier(0);
  op += NN;  // -> row 1

  for (int c = 0; c < NCHUNK; ++c) {
    const int buf = c & 1;

    if (c + 1 < NCHUNK) {
      // prefetch chunk c+1 into the other buffer (consumed 32 steps later)
      const float* ng = nzg + (size_t)(c + 1) * CHUNK * NN;
      const float* gg = ug + (size_t)(c + 1) * CHUNK * NIN;
      float* nl = &smNz[buf ^ 1][0];
      float* ul = &smU[buf ^ 1][0];
#pragma unroll
      for (int i = 0; i < 8; ++i)
        __builtin_amdgcn_global_load_lds((gu32*)(ng + i * 256 + n * 4),
                                         (lu32*)(nl + i * 256), 16, 0, 0);
#pragma unroll
      for (int j = 0; j < 3; ++j)
        __builtin_amdgcn_global_load_lds((gu32*)(gg + j * 64 + n),
                                         (lu32*)(ul + j * 64), 4, 0, 0);
      // Outstanding here: 11 loads(chunk c, oldest) + 32 stores + 11 loads(c+1).
      // vmcnt retires in issue order -> <=43 outstanding means chunk c landed.
      asm volatile("s_waitcnt vmcnt(43)" ::: "memory");
    } else {
      // last chunk: 11 loads(c) + 32 stores outstanding; no prefetch issued.
      asm volatile("s_waitcnt vmcnt(32)" ::: "memory");
    }
    __builtin_amdgcn_sched_barrier(0);

    const float* nzL = &smNz[buf][0] + n;  // per-lane column
    const float* uL  = &smU[buf][0];       // uniform rows
    const bool full = (c + 1 < NCHUNK);

#pragma unroll 4
    for (int st = 0; st < CHUNK; ++st) {
      // step t = 32c + st: s_{t+1} = 0.8 s + 0.2 relu(W_rec s + W_in u_t + sc*nz_t)
      const float nzc = nzL[st * NN];                       // ds_read_b32
      const v2f* u2 = (const v2f*)(uL + st * NIN);          // 3x ds_read_b64 (bcast)
      v2f a0 = v2f{SCALE * nzc, 0.0f};
      v2f a1 = v2f{0.0f, 0.0f}, a2 = v2f{0.0f, 0.0f}, a3 = v2f{0.0f, 0.0f};
      a0 = pk_fma(u2[0], win2[0], a0);
      a1 = pk_fma(u2[1], win2[1], a1);
      a2 = pk_fma(u2[2], win2[2], a2);
      const v4f* sv = (const v4f*)smS;                      // 16x ds_read_b128 (bcast)
#pragma unroll
      for (int q = 0; q < 16; q += 2) {
        const v4f qa = sv[q + 0];
        a0 = pk_fma(v2f{qa.x, qa.y}, w2[2 * q + 0], a0);
        a1 = pk_fma(v2f{qa.z, qa.w}, w2[2 * q + 1], a1);
        const v4f qb = sv[q + 1];
        a2 = pk_fma(v2f{qb.x, qb.y}, w2[2 * q + 2], a2);
        a3 = pk_fma(v2f{qb.z, qb.w}, w2[2 * q + 3], a3);
      }
      const v2f at = (a0 + a1) + (a2 + a3);
      const float pre = at.x + at.y;
      const float r = fmaxf(pre, 0.0f);
      s = fmaf(0.2f, r, 0.8f * s);
      smS[n] = s;                       // broadcast s_{t+1} (in-order DS)
      if (full || st < CHUNK - 1)       // t=1023 step is compute-only padding
        op[st * NN] = s;                // states[b][t+1][n], coalesced
    }
    op += CHUNK * NN;
  }
}

extern "C" void kernel_launch(void* const* d_in, const int* in_sizes, int n_in,
                              void* d_out, int out_size, void* d_ws, size_t ws_size,
                              hipStream_t stream) {
  const float* u     = (const float*)d_in[0];
  const float* noise = (const float*)d_in[1];
  const float* Wrec  = (const float*)d_in[2];
  const float* Win   = (const float*)d_in[3];
  float* out = (float*)d_out;

  const int B = in_sizes[0] / (TT * NIN);  // 512
  hipLaunchKernelGGL(rnn_scan_kernel, dim3(B), dim3(64), 0, stream,
                     u, noise, Wrec, Win, out);
}

// Round 4
// 208.702 us; speedup vs baseline: 2.2760x; 1.4150x over previous
//
#include <hip/hip_runtime.h>

typedef float v2f __attribute__((ext_vector_type(2)));
typedef float v4f __attribute__((ext_vector_type(4)));

#define TT 1024
#define NIN 6
#define NN 64
#define CHUNK 32
#define NCHUNK 32
#define SCALE 0.09486832980505137f  // sqrt(2*alpha*sigma_rec^2)

__device__ __forceinline__ v2f pk_fma(v2f a, v2f b, v2f c) {
  return __builtin_elementwise_fma(a, b, c);  // -> v_pk_fma_f32
}

typedef const __attribute__((address_space(1))) unsigned int gu32;
typedef __attribute__((address_space(3))) unsigned int lu32;

__global__ void __launch_bounds__(64) rnn_scan_kernel(
    const float* __restrict__ u, const float* __restrict__ noise,
    const float* __restrict__ Wrec, const float* __restrict__ Win,
    float* __restrict__ out) {
  const int b = blockIdx.x;
  const int n = threadIdx.x;  // lane owns state component n

  // Single wave per block: same-wave DS ops execute in order -> no barriers.
  // smHist: rolling state history. Step st reads row (st-1)&31, writes row st.
  // Row st of the previous chunk is dead by the time step st overwrites it.
  // NO global ops inside the step loop: a per-step global_store of s puts a
  // store-retire wait (WAR on the store-data VGPR) on the recurrence chain.
  __shared__ __align__(16) float smHist[CHUNK][NN];      // 8 KB
  __shared__ __align__(16) float smNz[2][CHUNK * NN];    // noise chunks (2x8KB)
  __shared__ __align__(16) float smU[2][CHUNK * NIN];    // u chunks (2x768B)

  const float* nzg = noise + (size_t)b * TT * NN;
  const float* ug  = u + (size_t)b * TT * NIN;
  float* outB = out + (size_t)b * TT * NN;

  // ---- stage chunk 0 (latency hidden behind the weight loads below)
#pragma unroll
  for (int i = 0; i < 8; ++i)
    __builtin_amdgcn_global_load_lds((gu32*)(nzg + i * 256 + n * 4),
                                     (lu32*)(&smNz[0][i * 256]), 16, 0, 0);
#pragma unroll
  for (int j = 0; j < 3; ++j)
    __builtin_amdgcn_global_load_lds((gu32*)(ug + j * 64 + n),
                                     (lu32*)(&smU[0][j * 64]), 4, 0, 0);

  // ---- per-lane weights: W_rec row n as 32 f32 pairs, W_in row n as 3 pairs
  v2f w2[NN / 2];
#pragma unroll
  for (int k = 0; k < NN; k += 4) {
    const float4 v = *reinterpret_cast<const float4*>(Wrec + n * NN + k);
    w2[k / 2 + 0] = v2f{v.x, v.y};
    w2[k / 2 + 1] = v2f{v.z, v.w};
  }
  v2f win2[3];
#pragma unroll
  for (int j = 0; j < 3; ++j)
    win2[j] = v2f{Win[n * NIN + 2 * j + 0], Win[n * NIN + 2 * j + 1]};

  float s = 0.0f;
  smHist[CHUNK - 1][n] = 0.0f;  // s_0 (read by step st=0 of chunk 0)
  outB[n] = 0.0f;               // states[:,0,:] = 0

  // Drain everything once (weights + chunk0 + zero-store) -> clean vmcnt
  // accounting for the hand-counted waits below.
  asm volatile("s_waitcnt vmcnt(0)" ::: "memory");
  __builtin_amdgcn_sched_barrier(0);

  for (int c = 0; c < NCHUNK; ++c) {
    const int buf = c & 1;

    if (c + 1 < NCHUNK) {
      // prefetch chunk c+1 into the other buffer (consumed 32 steps later)
      const float* ng = nzg + (size_t)(c + 1) * CHUNK * NN;
      const float* gg = ug + (size_t)(c + 1) * CHUNK * NIN;
      float* nl = &smNz[buf ^ 1][0];
      float* ul = &smU[buf ^ 1][0];
#pragma unroll
      for (int i = 0; i < 8; ++i)
        __builtin_amdgcn_global_load_lds((gu32*)(ng + i * 256 + n * 4),
                                         (lu32*)(nl + i * 256), 16, 0, 0);
#pragma unroll
      for (int j = 0; j < 3; ++j)
        __builtin_amdgcn_global_load_lds((gu32*)(gg + j * 64 + n),
                                         (lu32*)(ul + j * 64), 4, 0, 0);
      // Outstanding (oldest->newest): 11 loads(chunk c) + 8 stores(chunk c-1
      // epilogue) + 11 loads(chunk c+1). vmcnt retires in issue order ->
      // <=19 outstanding means chunk c's loads landed.
      asm volatile("s_waitcnt vmcnt(19)" ::: "memory");
    } else {
      // last chunk: 11 loads(c) + 8 stores(c-1); no prefetch issued.
      asm volatile("s_waitcnt vmcnt(8)" ::: "memory");
    }
    __builtin_amdgcn_sched_barrier(0);

    const float* nzL = &smNz[buf][0] + n;  // per-lane column
    const float* uL  = &smU[buf][0];       // uniform rows

#pragma unroll 4
    for (int st = 0; st < CHUNK; ++st) {
      // step t = 32c+st: s_{t+1} = 0.8 s + 0.2 relu(W_rec s + W_in u_t + sc*nz)
      const int prev = (st + CHUNK - 1) & (CHUNK - 1);
      const float nzc = nzL[st * NN];                    // ds_read_b32
      const v2f* u2 = (const v2f*)(uL + st * NIN);       // 3x ds_read_b64 bcast
      v2f a0 = v2f{SCALE * nzc, 0.0f};
      v2f a1 = v2f{0.0f, 0.0f}, a2 = v2f{0.0f, 0.0f}, a3 = v2f{0.0f, 0.0f};
      a0 = pk_fma(u2[0], win2[0], a0);
      a1 = pk_fma(u2[1], win2[1], a1);
      a2 = pk_fma(u2[2], win2[2], a2);
      const v4f* sv = (const v4f*)(&smHist[prev][0]);    // 16x ds_read_b128 bcast
#pragma unroll
      for (int q = 0; q < 16; q += 2) {
        const v4f qa = sv[q + 0];
        a0 = pk_fma(v2f{qa.x, qa.y}, w2[2 * q + 0], a0);
        a1 = pk_fma(v2f{qa.z, qa.w}, w2[2 * q + 1], a1);
        const v4f qb = sv[q + 1];
        a2 = pk_fma(v2f{qb.x, qb.y}, w2[2 * q + 2], a2);
        a3 = pk_fma(v2f{qb.z, qb.w}, w2[2 * q + 3], a3);
      }
      const v2f at = (a0 + a1) + (a2 + a3);
      const float pre = at.x + at.y;
      const float r = fmaxf(pre, 0.0f);
      s = fmaf(0.2f, r, 0.8f * s);
      smHist[st][n] = s;  // in-order DS: visible to next step's bcast reads
    }

    // ---- chunk epilogue: dump 32 state rows (output rows 32c+1..32c+32).
    // Lane n covers row (n>>4) of each 4-row group, comps (n&15)*4..+3.
    v4f st4[8];
    const float* hbase = &smHist[0][0] + (n >> 4) * NN + (n & 15) * 4;
#pragma unroll
    for (int i = 0; i < 8; ++i)
      st4[i] = *(const v4f*)(hbase + i * 4 * NN);       // 8x ds_read_b128

    float* gp = outB + (size_t)(c * CHUNK + 1) * NN + (n >> 4) * NN + (n & 15) * 4;
    if (c + 1 < NCHUNK) {
#pragma unroll
      for (int i = 0; i < 8; ++i)
        *(v4f*)(gp + (size_t)i * 4 * NN) = st4[i];      // 8x store_dwordx4
    } else {
      // last chunk: rows 993..1023 only (row 1024 doesn't exist)
#pragma unroll
      for (int i = 0; i < 7; ++i)
        *(v4f*)(gp + (size_t)i * 4 * NN) = st4[i];
      if (n < 48)  // rows 1021..1023
        *(v4f*)(gp + (size_t)7 * 4 * NN) = st4[7];
    }
  }
}

extern "C" void kernel_launch(void* const* d_in, const int* in_sizes, int n_in,
                              void* d_out, int out_size, void* d_ws, size_t ws_size,
                              hipStream_t stream) {
  const float* u     = (const float*)d_in[0];
  const float* noise = (const float*)d_in[1];
  const float* Wrec  = (const float*)d_in[2];
  const float* Win   = (const float*)d_in[3];
  float* out = (float*)d_out;

  const int B = in_sizes[0] / (TT * NIN);  // 512
  hipLaunchKernelGGL(rnn_scan_kernel, dim3(B), dim3(64), 0, stream,
                     u, noise, Wrec, Win, out);
}